// Round 1
// baseline (206.635 us; speedup 1.0000x reference)
//
#include <hip/hip_runtime.h>

// yoloLoss on MI355X — memory-bound streaming reduction.
// pred/target: (4096,14,14,30) fp32. Output: scalar fp32.
// Total read = 192.7 MB -> HBM-bound floor ~31 us at 6.3 TB/s.

#define FEAT 30               // B*5 + C = 2*5 + 20
#define CELLS 802816          // 4096*14*14
#define TPB 256               // threads per block
#define CPB 256               // cells per block (1 cell/thread)
#define NBLOCKS (CELLS / CPB) // 3136 exactly
#define F4_PER_TILE (CPB * FEAT / 4) // 1920 float4 per array per tile

__device__ __forceinline__ float iou_f(float x1, float y1, float w1, float h1,
                                       float x2, float y2, float w2, float h2) {
    float b1x1 = x1 - 0.5f * w1, b1x2 = x1 + 0.5f * w1;
    float b1y1 = y1 - 0.5f * h1, b1y2 = y1 + 0.5f * h1;
    float b2x1 = x2 - 0.5f * w2, b2x2 = x2 + 0.5f * w2;
    float b2y1 = y2 - 0.5f * h2, b2y2 = y2 + 0.5f * h2;
    float iw = fmaxf(fminf(b1x2, b2x2) - fmaxf(b1x1, b2x1), 0.0f);
    float ih = fmaxf(fminf(b1y2, b2y2) - fmaxf(b1y1, b2y1), 0.0f);
    float inter = iw * ih;
    float a1 = (b1x2 - b1x1) * (b1y2 - b1y1);
    float a2 = (b2x2 - b2x1) * (b2y2 - b2y1);
    return inter / (a1 + a2 - inter + 1e-6f);
}

__global__ __launch_bounds__(TPB) void yolo_main_kernel(
        const float* __restrict__ pred, const float* __restrict__ tgt,
        float* __restrict__ partials) {
    // 60 KB LDS: 2 blocks/CU (LDS-limited), 8 waves/CU.
    __shared__ float sp[CPB * FEAT];
    __shared__ float st[CPB * FEAT];
    __shared__ float wave_sum[TPB / 64];

    const int tid = threadIdx.x;
    const long long base = (long long)blockIdx.x * (CPB * FEAT);

    // Stage tile: fully coalesced float4 loads. Tile base byte offset =
    // blockIdx*30720, 16B-aligned; 1920 float4 per array.
    const float4* gp = (const float4*)(pred + base);
    const float4* gt = (const float4*)(tgt + base);
    float4* lp = (float4*)sp;
    float4* lt = (float4*)st;
#pragma unroll
    for (int i = 0; i < 7; ++i) {
        lp[tid + i * TPB] = gp[tid + i * TPB];
        lt[tid + i * TPB] = gt[tid + i * TPB];
    }
    if (tid < (F4_PER_TILE - 7 * TPB)) { // tail: 128 float4
        lp[tid + 7 * TPB] = gp[tid + 7 * TPB];
        lt[tid + 7 * TPB] = gt[tid + 7 * TPB];
    }
    __syncthreads();

    // LDS -> registers: 15 float2 per array (cell stride 120 B, 8B-aligned).
    float p[FEAT], t[FEAT];
    const float2* pc = (const float2*)(sp + tid * FEAT);
    const float2* tc = (const float2*)(st + tid * FEAT);
#pragma unroll
    for (int i = 0; i < FEAT / 2; ++i) {
        float2 vp = pc[i]; p[2 * i] = vp.x; p[2 * i + 1] = vp.y;
        float2 vt = tc[i]; t[2 * i] = vt.x; t[2 * i + 1] = vt.y;
    }

    // --- per-cell YOLO loss (mirrors the JAX reference exactly) ---
    const bool obj0 = t[4] > 0.0f;   // box0 conf target
    const bool obj1 = t[9] > 0.0f;   // box1 conf target
    const float mf = obj0 ? 1.0f : 0.0f; // has_obj = obj_mask[...,0]

    // noobj conf loss (per box, where target conf == 0)
    float d0 = p[4] - t[4];
    float d1 = p[9] - t[9];
    float noobj = (obj0 ? 0.0f : d0 * d0) + (obj1 ? 0.0f : d1 * d1);

    // best box by IoU; argmax ties -> index 0
    float iou0 = iou_f(p[0], p[1], p[2], p[3], t[0], t[1], t[2], t[3]);
    float iou1 = iou_f(p[5], p[6], p[7], p[8], t[5], t[6], t[7], t[8]);
    const bool sel1 = iou1 > iou0;

    // selects instead of dynamic indexing (keeps p[]/t[] in registers)
    float pbx = sel1 ? p[5] : p[0];
    float pby = sel1 ? p[6] : p[1];
    float pbw = sel1 ? p[7] : p[2];
    float pbh = sel1 ? p[8] : p[3];
    float pbc = sel1 ? p[9] : p[4];
    float tbx = sel1 ? t[5] : t[0];
    float tby = sel1 ? t[6] : t[1];
    float tbw = sel1 ? t[7] : t[2];
    float tbh = sel1 ? t[8] : t[3];
    float tbc = sel1 ? t[9] : t[4];

    float dx = pbx - tbx, dy = pby - tby;
    float xy = dx * dx + dy * dy;

    float pw = sqrtf(fabsf(pbw) + 1e-6f);
    float ph = sqrtf(fabsf(pbh) + 1e-6f);
    float tw = sqrtf(obj0 ? tbw : 1.0f); // t_wh_safe: avoids NaN when !obj
    float th = sqrtf(obj0 ? tbh : 1.0f);
    float dw = pw - tw, dh = ph - th;
    float wh = dw * dw + dh * dh;

    float dc = pbc - tbc;
    float obj_l = dc * dc;

    // nonbest conf: LAMBDA_NOOBJ applied here AND again in total (ref does both)
    float nonbest = (p[4] + p[9]) - pbc;
    noobj += 0.5f * mf * nonbest * nonbest;

    float cls = 0.0f;
#pragma unroll
    for (int k = 10; k < FEAT; ++k) {
        float d = p[k] - t[k];
        cls += d * d;
    }

    float cell = 5.0f * mf * (xy + wh) + mf * obj_l + 0.5f * noobj + mf * cls;

    // --- block reduction: wave shuffle then LDS across 4 waves ---
    float v = cell;
#pragma unroll
    for (int off = 32; off > 0; off >>= 1) v += __shfl_down(v, off, 64);
    __syncthreads(); // sp/st reuse safety not needed, but wave_sum ordering is
    if ((tid & 63) == 0) wave_sum[tid >> 6] = v;
    __syncthreads();
    if (tid == 0)
        partials[blockIdx.x] = wave_sum[0] + wave_sum[1] + wave_sum[2] + wave_sum[3];
}

__global__ __launch_bounds__(TPB) void yolo_reduce_kernel(
        const float* __restrict__ partials, float* __restrict__ out) {
    __shared__ float wave_sum[TPB / 64];
    const int tid = threadIdx.x;
    float v = 0.0f;
    for (int i = tid; i < NBLOCKS; i += TPB) v += partials[i];
#pragma unroll
    for (int off = 32; off > 0; off >>= 1) v += __shfl_down(v, off, 64);
    if ((tid & 63) == 0) wave_sum[tid >> 6] = v;
    __syncthreads();
    if (tid == 0)
        out[0] = (wave_sum[0] + wave_sum[1] + wave_sum[2] + wave_sum[3]) *
                 (1.0f / 4096.0f);
}

extern "C" void kernel_launch(void* const* d_in, const int* in_sizes, int n_in,
                              void* d_out, int out_size, void* d_ws, size_t ws_size,
                              hipStream_t stream) {
    const float* pred = (const float*)d_in[0];
    const float* tgt  = (const float*)d_in[1];
    float* out = (float*)d_out;
    float* partials = (float*)d_ws; // 3136 floats = 12.5 KB, << ws_size

    yolo_main_kernel<<<NBLOCKS, TPB, 0, stream>>>(pred, tgt, partials);
    yolo_reduce_kernel<<<1, TPB, 0, stream>>>(partials, out);
}